// Round 3
// baseline (95.929 us; speedup 1.0000x reference)
//
#include <hip/hip_runtime.h>
#include <math.h>

#define BS 8
#define CIN 64
#define COUT 64
#define SDIM 512
#define NBANK 4
#define DSZ 32
#define SPATIAL (DSZ*DSZ*DSZ)
#define NTAP 27
#define CH 8                  // ic per chunk
#define NCH 8                 // chunks
#define KROW 216              // shorts per A row: 27 taps * 8 ic, no pad
#define NKS 7                 // K-steps (last one 3/4 useful, hi==3 masked)
// xP windowed layout: per (b,ch) slab = 1124 rows x 33 texels (texel=16B=8 bf16)
//   rows 0..33 zero | zin=0..31: 32 interior rows + 1 zero row | rows 1090..1123 zero
//   interior row texel 0 = zero (shared x-pad), texels 1..32 = x=0..31
#define SLABTEX (1124*33)     // 37092 texels per (b,ch)
#define WINTEX 3301           // 3-plane window: rows 33z .. 33z+100 + 1 texel
#define XSTEX 3301
#define ATEX 1728             // 64 oc * 216 shorts = 27648 B = 1728 texels
constexpr float EPS = 1e-8f;

typedef short bf16x8 __attribute__((ext_vector_type(8)));
typedef float f32x4 __attribute__((ext_vector_type(4)));

#define XP_TEXELS (64*SLABTEX)          // 8 b * 8 ch slabs
#define WA_TEXELS (64*ATEX)

__device__ __forceinline__ unsigned pack2(float a, float b) {
    unsigned ua = __float_as_uint(a);
    unsigned ub = __float_as_uint(b);
    ua = (ua + 0x7fffu + ((ua >> 16) & 1u)) >> 16;
    ub = (ub + 0x7fffu + ((ub >> 16) & 1u)) & 0xffff0000u;
    return ua | ub;
}
__device__ __forceinline__ unsigned short bf16r(float f) {
    unsigned u = __float_as_uint(f);
    u = (u + 0x7fffu + ((u >> 16) & 1u)) >> 16;
    return (unsigned short)u;
}

// async global->LDS DMA, 16B per lane; l must be wave-uniform (HW adds lane*16)
__device__ __forceinline__ void gload_lds16(const int4* g, int4* l) {
    __builtin_amdgcn_global_load_lds(
        (const __attribute__((address_space(1))) unsigned int*)(const void*)g,
        (__attribute__((address_space(3))) unsigned int*)(void*)l, 16, 0, 0);
}

// ---------------------------------------------------------------------------
// Kernel 0: style vectors. grid=BS, 64 threads.
// ---------------------------------------------------------------------------
__global__ void prep_style(const float* __restrict__ w,
                           const float* __restrict__ filter_w,
                           const float* __restrict__ filter_b,
                           const float* __restrict__ mod_w,
                           const float* __restrict__ mod_b,
                           float* __restrict__ fwt,
                           float* __restrict__ mod) {
    const int b = blockIdx.x;
    const int t = threadIdx.x;
    const float* wb = w + b * SDIM;
    __shared__ float lg[NBANK];

    if (t < NBANK) {
        float s = filter_b[t];
        const float* fr = filter_w + t * SDIM;
        for (int j = 0; j < SDIM; ++j) s += wb[j] * fr[j];
        lg[t] = s;
    }
    __syncthreads();
    if (t == 0) {
        float m = lg[0];
        for (int n = 1; n < NBANK; ++n) m = fmaxf(m, lg[n]);
        float e[NBANK];
        float s = 0.0f;
        for (int n = 0; n < NBANK; ++n) { e[n] = expf(lg[n] - m); s += e[n]; }
        for (int n = 0; n < NBANK; ++n) fwt[b * NBANK + n] = e[n] / s;
    }
    {
        float s = mod_b[t];
        const float* mr = mod_w + t * SDIM;
        for (int j = 0; j < SDIM; ++j) s += wb[j] * mr[j];
        mod[b * CIN + t] = s;
    }
}

// ---------------------------------------------------------------------------
// Kernel 1: blended+modulated+demodulated weights -> bf16 MFMA layout
// wA rows: (b,ch,oc) -> 216 shorts, k = tap*8 + icl. grid=(COUT,BS), 64 thr.
// ---------------------------------------------------------------------------
__global__ void prep_weights(const float* __restrict__ bank,
                             const float* __restrict__ fwt,
                             const float* __restrict__ mod,
                             unsigned short* __restrict__ wA) {
    const int oc = blockIdx.x;
    const int b  = blockIdx.y;
    const int ic = threadIdx.x;

    const float f0 = fwt[b * NBANK + 0];
    const float f1 = fwt[b * NBANK + 1];
    const float f2 = fwt[b * NBANK + 2];
    const float f3 = fwt[b * NBANK + 3];
    const float m  = mod[b * CIN + ic];

    const float* b0 = bank + (size_t)((0 * COUT + oc) * CIN + ic) * NTAP;
    const float* b1 = bank + (size_t)((1 * COUT + oc) * CIN + ic) * NTAP;
    const float* b2 = bank + (size_t)((2 * COUT + oc) * CIN + ic) * NTAP;
    const float* b3 = bank + (size_t)((3 * COUT + oc) * CIN + ic) * NTAP;

    float v[NTAP];
    float ss = 0.0f;
#pragma unroll
    for (int k = 0; k < NTAP; ++k) {
        float t = f0 * b0[k] + f1 * b1[k] + f2 * b2[k] + f3 * b3[k];
        t *= m;
        v[k] = t;
        ss += t * t;
    }
#pragma unroll
    for (int off = 32; off >= 1; off >>= 1) ss += __shfl_xor(ss, off, 64);
    const float d = rsqrtf(ss + EPS);

    const int chunk = ic >> 3, icl = ic & 7;
    unsigned short* row = wA + ((size_t)((b * NCH + chunk) * COUT + oc)) * KROW;
#pragma unroll
    for (int k = 0; k < NTAP; ++k) row[k * CH + icl] = bf16r(v[k] * d);
}

// ---------------------------------------------------------------------------
// Kernel 2: x -> xP windowed padded bf16 texel layout.
// grid=(34, NCH, BS), 256 threads. zidx<32: one interior plane (33 rows);
// zidx=32: leading 34 zero rows; zidx=33: trailing 34 zero rows.
// ---------------------------------------------------------------------------
__global__ __launch_bounds__(256) void xform(const float* __restrict__ x,
                                             int4* __restrict__ xP) {
    const int zidx = blockIdx.x;
    const int ch   = blockIdx.y;
    const int b    = blockIdx.z;
    int4* slab = xP + (size_t)(b * NCH + ch) * SLABTEX;
    const int t = threadIdx.x;
    const int4 z4 = make_int4(0, 0, 0, 0);

    if (zidx >= 32) {
        int base = (zidx == 32) ? 0 : 1090 * 33;
        for (int p = t; p < 34 * 33; p += 256) slab[base + p] = z4;
        return;
    }
    const float* xc = x + ((size_t)b * CIN + ch * CH) * SPATIAL + zidx * 1024;
    int4* dst = slab + (34 + 33 * zidx) * 33;
    for (int p = t; p < 33 * 33; p += 256) {
        const int r  = p / 33;
        const int cx = p - r * 33;
        int4 v = z4;
        if (r < 32 && cx > 0) {
            const float* s = xc + r * 32 + (cx - 1);
            v.x = (int)pack2(s[0 * SPATIAL], s[1 * SPATIAL]);
            v.y = (int)pack2(s[2 * SPATIAL], s[3 * SPATIAL]);
            v.z = (int)pack2(s[4 * SPATIAL], s[5 * SPATIAL]);
            v.w = (int)pack2(s[6 * SPATIAL], s[7 * SPATIAL]);
        }
        dst[p] = v;
    }
}

// ---------------------------------------------------------------------------
// Kernel 3: implicit-GEMM conv3d, async-DMA double-buffered pipeline.
// grid=256 (bid&7=b, bid>>3=z), 512 threads (8 waves), 1 block/CU.
// ---------------------------------------------------------------------------
__global__ __launch_bounds__(512, 2) void conv3d_mfma(
        const int4* __restrict__ xP,
        const int4* __restrict__ wA,
        float* __restrict__ out) {
    const int bid = blockIdx.x;
    const int b = bid & 7, z = bid >> 3;
    const int t  = threadIdx.x;
    const int ln = t & 15;
    const int hi = (t >> 4) & 3;
    const int wv = t >> 6;

    // texel map: xs0[0,3301) xs1[3301,6602) A0[6602,8330) A1[8330,10058) +pad
    __shared__ int4 smem[2 * XSTEX + 2 * ATEX + 4];

    // per-lane B tap offsets (bytes): tap = ks*4+hi; 27 -> 0 (A masked to 0)
    int offB[NKS];
#pragma unroll
    for (int ks = 0; ks < NKS; ++ks) {
        int tap = ks * 4 + hi;
        if (tap > 26) tap = 0;
        const int dz = tap / 9, r = tap - dz * 9, dy = r / 3, dx = r - dy * 3;
        offB[ks] = (dz * 1089 + dy * 33 + dx) * 16;
    }
    int baseB[8];
#pragma unroll
    for (int st = 0; st < 8; ++st)
        baseB[st] = ((wv * 4 + (st >> 1)) * 33 + (st & 1) * 16 + ln) * 16;
    const int baseA = ln * 432 + hi * 16;       // bytes within A chunk region

    const size_t slab0 = (size_t)(b * NCH) * SLABTEX;
    const int win = z * 1089;

    int4 xt, at4;
    // ---- stage chunk c into buffer buf ----
    auto stage = [&](int c, int buf) {
        const int4* xsrc = xP + slab0 + (size_t)c * SLABTEX + win;
        const int4* asrc = wA + (size_t)(b * NCH + c) * ATEX;
        int4* lx = smem + buf * XSTEX;
        int4* la = smem + 2 * XSTEX + buf * ATEX;
        const int wb = (t & ~63);               // wave-uniform lane-0 index
#pragma unroll
        for (int i = 0; i < 6; ++i)
            gload_lds16(xsrc + i * 512 + t, lx + i * 512 + wb);
#pragma unroll
        for (int i = 0; i < 3; ++i)
            gload_lds16(asrc + i * 512 + t, la + i * 512 + wb);
        if (t < WINTEX - 3072) xt  = xsrc[3072 + t];
        if (t < ATEX - 1536)   at4 = asrc[1536 + t];
    };
    auto wtails = [&](int buf) {
        if (t < WINTEX - 3072) smem[buf * XSTEX + 3072 + t] = xt;
        if (t < ATEX - 1536)   smem[2 * XSTEX + buf * ATEX + 1536 + t] = at4;
    };

    f32x4 acc[4][8];
#pragma unroll
    for (int i = 0; i < 4; ++i)
#pragma unroll
        for (int j = 0; j < 8; ++j) acc[i][j] = (f32x4){0.f, 0.f, 0.f, 0.f};

    stage(0, 0);
    wtails(0);
    __syncthreads();

    const bf16x8 zv = {0, 0, 0, 0, 0, 0, 0, 0};

    for (int c = 0; c < NCH; ++c) {
        if (c < NCH - 1) stage(c + 1, (c + 1) & 1);   // async, lands during MFMA

        const char* Xb = (const char*)(smem + (c & 1) * XSTEX);
        const char* Ab = (const char*)(smem + 2 * XSTEX + (c & 1) * ATEX);
#pragma unroll
        for (int ks = 0; ks < NKS; ++ks) {
            bf16x8 a[4];
#pragma unroll
            for (int at = 0; at < 4; ++at) {
                bf16x8 av = *(const bf16x8*)(Ab + at * 6912 + baseA + ks * 64);
                if (ks == NKS - 1) a[at] = (hi == 3) ? zv : av;
                else               a[at] = av;
            }
            bf16x8 bfr[8];
#pragma unroll
            for (int st = 0; st < 8; ++st)
                bfr[st] = *(const bf16x8*)(Xb + baseB[st] + offB[ks]);
#pragma unroll
            for (int at = 0; at < 4; ++at)
#pragma unroll
                for (int st = 0; st < 8; ++st)
                    acc[at][st] = __builtin_amdgcn_mfma_f32_16x16x32_bf16(
                        a[at], bfr[st], acc[at][st], 0, 0, 0);
        }
        if (c < NCH - 1) {
            wtails((c + 1) & 1);     // vmcnt wait here is cheap: loads aged a full MFMA phase
            __syncthreads();
        }
    }

    // ---- epilogue: D col=lane&15, row=(lane>>4)*4+reg (verified R2) ----
    float* ob = out + (size_t)b * COUT * SPATIAL + (size_t)z * 1024;
#pragma unroll
    for (int at = 0; at < 4; ++at) {
        const int oc = at * 16 + hi * 4;
#pragma unroll
        for (int st = 0; st < 8; ++st) {
            const int sp = (wv * 4 + (st >> 1)) * 32 + (st & 1) * 16 + ln;
#pragma unroll
            for (int r = 0; r < 4; ++r)
                ob[(size_t)(oc + r) * SPATIAL + sp] = acc[at][st][r];
        }
    }
}

// ---------------------------------------------------------------------------
extern "C" void kernel_launch(void* const* d_in, const int* in_sizes, int n_in,
                              void* d_out, int out_size, void* d_ws, size_t ws_size,
                              hipStream_t stream) {
    const float* x        = (const float*)d_in[0];
    const float* w        = (const float*)d_in[1];
    const float* filter_w = (const float*)d_in[2];
    const float* filter_b = (const float*)d_in[3];
    const float* mod_w    = (const float*)d_in[4];
    const float* mod_b    = (const float*)d_in[5];
    const float* bank     = (const float*)d_in[6];
    float* out = (float*)d_out;

    int4* xP = (int4*)d_ws;
    int4* wA = xP + XP_TEXELS;
    float* fwt = (float*)(wA + WA_TEXELS);
    float* mod = fwt + BS * NBANK;

    prep_style<<<BS, 64, 0, stream>>>(w, filter_w, filter_b, mod_w, mod_b, fwt, mod);
    prep_weights<<<dim3(COUT, BS), 64, 0, stream>>>(bank, fwt, mod,
                                                    (unsigned short*)wA);
    xform<<<dim3(34, NCH, BS), 256, 0, stream>>>(x, xP);
    conv3d_mfma<<<256, 512, 0, stream>>>(xP, wA, out);
}